// Round 7
// baseline (136.337 us; speedup 1.0000x reference)
//
#include <hip/hip_runtime.h>

// Problem constants
#define NB   16
#define CIN  256
#define COUT 256
#define HH   32
#define WW   32
#define HW   1024           // 32*32
#define KK   9
#define CK   2304           // CIN*KK  (ordered k*256 + c, tap-major)

typedef __bf16 bf16x8 __attribute__((ext_vector_type(8)));
typedef float  f32x4  __attribute__((ext_vector_type(4)));

__device__ __forceinline__ unsigned short f2bf(float f) {
    unsigned int u = __float_as_uint(f);
    u += 0x7FFFu + ((u >> 16) & 1u);          // round-nearest-even
    return (unsigned short)(u >> 16);
}
__device__ __forceinline__ float bfhi(unsigned int u) {   // high bf16 -> f32
    return __uint_as_float(u & 0xFFFF0000u);
}
__device__ __forceinline__ float bflo(unsigned int u) {   // low bf16 -> f32
    return __uint_as_float(u << 16);
}

typedef const __attribute__((address_space(1))) void* gas_ptr;
typedef __attribute__((address_space(3))) void* las_ptr;

__device__ __forceinline__ void async16(const void* g, void* l) {
    __builtin_amdgcn_global_load_lds((gas_ptr)g, (las_ptr)l, 16, 0, 0);
}

// ---------------------------------------------------------------- wconv ----
// weight fp32 [O][C][3][3] -> bf16 [O][k*256+c]  (tap-major)
__global__ __launch_bounds__(256) void wconv_kernel(const float* __restrict__ w,
                                                    unsigned short* __restrict__ wbf) {
    __shared__ float ls[CK];
    const int o = blockIdx.x;
    const float* wo = w + (size_t)o * CK;
#pragma unroll
    for (int i = threadIdx.x; i < CK; i += 256) ls[i] = wo[i];
    __syncthreads();
    unsigned short* dst = wbf + (size_t)o * CK;
#pragma unroll
    for (int i = threadIdx.x; i < CK; i += 256) {
        int k = i >> 8, c = i & 255;
        dst[i] = f2bf(ls[c * KK + k]);        // bank stride 9: conflict-free
    }
}

// ------------------------------------------------------------------- xt ----
// x fp32 [n][c][hw] -> xtb bf16 [n][hw][c]   (64x64 LDS tile transpose)
__global__ __launch_bounds__(256) void xt_kernel(const float* __restrict__ x,
                                                 unsigned short* __restrict__ xtb) {
    __shared__ float ls[64][65];
    const int c0  = blockIdx.x * 64;
    const int hw0 = blockIdx.y * 64;
    const int n   = blockIdx.z;
    const int t   = threadIdx.x;
    {
        int c = t >> 2, q = t & 3;
        const float4* base = (const float4*)(x + ((size_t)(n * CIN + c0 + c)) * HW + hw0 + q * 16);
#pragma unroll
        for (int j = 0; j < 4; ++j) {
            float4 v = base[j];
            ls[c][q * 16 + j * 4 + 0] = v.x;
            ls[c][q * 16 + j * 4 + 1] = v.y;
            ls[c][q * 16 + j * 4 + 2] = v.z;
            ls[c][q * 16 + j * 4 + 3] = v.w;
        }
    }
    __syncthreads();
    {
        int hw = t >> 2, seg = (t & 3) * 16;
        unsigned int dw[8];
#pragma unroll
        for (int j = 0; j < 8; ++j) {
            float f0 = ls[seg + 2 * j][hw];
            float f1 = ls[seg + 2 * j + 1][hw];
            dw[j] = (unsigned)f2bf(f0) | ((unsigned)f2bf(f1) << 16);
        }
        uint4* dst = (uint4*)(xtb + ((size_t)(n * HW + hw0 + hw)) * CIN + c0 + seg);
        dst[0] = *(uint4*)&dw[0];
        dst[1] = *(uint4*)&dw[4];
    }
}

// ---------------------------------------------------------------- fused ----
// Per block: out[0..255][hw0..hw0+63] for one image. BM=256, BN=64, BK=64.
// 512 threads / 8 waves, WAVE-SPECIALIZED:
//   waves 0..3  = consumers: wave-tile 64(o) x 64(hw), acc[4][4],
//                 16 ds_read_b128 + 32 MFMA per step.
//   waves 4..7  = producers: corner prefetch (global), bilinear lerp,
//                 ds_write B-tile, A-tile lds-DMA.
// One barrier per step; producer VALU runs concurrently with consumer
// LDS/MFMA on the other waves (different pipes co-issue). Double-buffered
// LDS (As[2] 64KB + Bs[2] 16KB = 80KB). 36 steps of BK=64 (ck = step*64,
// tap-major). XCD-aware block decode keeps each image's xtb slice + wbf in
// one XCD's L2.
__global__ __launch_bounds__(512, 2) void fused_kernel(const unsigned short* __restrict__ wbf,
                                                       const unsigned short* __restrict__ xtb,
                                                       const float* __restrict__ off,
                                                       float* __restrict__ out) {
    __shared__ unsigned short As[2][256 * 64];   // 64 KB
    __shared__ unsigned short Bs[2][64 * 64];    // 16 KB

    const int tid  = threadIdx.x;
    const int wv   = tid >> 6;
    const int lane = tid & 63;

    // XCD-aware decode (consecutive ids round-robin XCDs)
    const int id  = blockIdx.x;
    const int n   = ((id & 7) << 1) | ((id >> 3) & 1);
    const int hw0 = (id >> 4) * 64;

    const bool producer = (wv >= 4);

    // ---------------- consumer state
    const int quad = lane >> 4;
    const int l15  = lane & 15;
    f32x4 acc[4][4] = {};

    // ---------------- producer state
    const int ptid = (wv - 4) * 64 + lane;    // 0..255 when producer
    const int hwl  = ptid >> 2;               // 0..63  (B row)
    const int segq = ptid & 3;                // 16-channel group
    const int hw   = hw0 + (hwl & 63);
    const int h    = hw >> 5, w = hw & 31;
    const int pv   = wv - 4;                  // 0..3
    const int srow   = lane >> 3;
    const int schunk = (lane & 7) ^ (srow & 7);

    const uint4*  xb4  = (const uint4*)(xtb + (size_t)n * HW * CIN);
    const float2* offp = (const float2*)(off + ((size_t)n * HW + hw) * (2 * KK));

    // producer double register sets (explicit, no dynamic indexing)
    float wgs0[4], wgs1[4];
    uint4 crs0[8], crs1[8];

    // prefetch corners + weights for step t into (wg, cr)
    auto prefetch = [&](int t, float* wg, uint4* cr) {
        int tap = t >> 2, sub = t & 3;
        float2 o = offp[tap];
        float py = (float)(h + tap / 3 - 1) + o.x;
        float px = (float)(w + tap % 3 - 1) + o.y;
        float y0f = floorf(py), x0f = floorf(px);
        float ly = py - y0f, lx = px - x0f;
        int y0 = (int)y0f, x0 = (int)x0f;
#pragma unroll
        for (int c2 = 0; c2 < 4; ++c2) {
            int yy = y0 + (c2 >> 1);
            int xx = x0 + (c2 & 1);
            float wy = (c2 >> 1) ? ly : 1.0f - ly;
            float wx = (c2 & 1) ? lx : 1.0f - lx;
            bool v = (yy >= 0) && (yy < HH) && (xx >= 0) && (xx < WW);
            wg[c2] = v ? wy * wx : 0.0f;
            int yc = yy < 0 ? 0 : (yy > HH - 1 ? HH - 1 : yy);
            int xc = xx < 0 ? 0 : (xx > WW - 1 ? WW - 1 : xx);
            int ridx = yc * WW + xc;
            const uint4* rp = xb4 + (size_t)ridx * 32 + sub * 8 + segq * 2;
            cr[2 * c2]     = rp[0];
            cr[2 * c2 + 1] = rp[1];
        }
    };

    // stage step t into buffer nb: lerp->Bs (consumes cr, waits old vmcnt),
    // then A-DMA (drained by this step's barrier), prefetch issued after.
    auto build = [&](int nb, int t, const float* wg, const uint4* cr) {
#pragma unroll
        for (int p = 0; p < 2; ++p) {
            unsigned u0[4], u1[4], u2[4], u3[4];
            *(uint4*)u0 = cr[0 + p]; *(uint4*)u1 = cr[2 + p];
            *(uint4*)u2 = cr[4 + p]; *(uint4*)u3 = cr[6 + p];
            unsigned dw[4];
#pragma unroll
            for (int d = 0; d < 4; ++d) {
                float lo = wg[0] * bflo(u0[d]) + wg[1] * bflo(u1[d])
                         + wg[2] * bflo(u2[d]) + wg[3] * bflo(u3[d]);
                float hi = wg[0] * bfhi(u0[d]) + wg[1] * bfhi(u1[d])
                         + wg[2] * bfhi(u2[d]) + wg[3] * bfhi(u3[d]);
                dw[d] = (unsigned)f2bf(lo) | ((unsigned)f2bf(hi) << 16);
            }
            *(uint4*)&Bs[nb][hwl * 64 + ((segq * 2 + p) ^ (hwl & 7)) * 8] = *(uint4*)dw;
        }
#pragma unroll
        for (int j = 0; j < 8; ++j) {
            int rb = pv * 64 + j * 8;
            async16(wbf + (size_t)(rb + srow) * CK + t * 64 + schunk * 8,
                    &As[nb][rb * 64]);
        }
    };

    auto mfma_step = [&](int pb) {
        bf16x8 af[4][2], bfr[4][2];
#pragma unroll
        for (int mi = 0; mi < 4; ++mi)
#pragma unroll
            for (int hh = 0; hh < 2; ++hh) {
                int row = wv * 64 + mi * 16 + l15;
                int ch  = (hh * 4 + quad) ^ (row & 7);
                af[mi][hh] = *(const bf16x8*)&As[pb][row * 64 + ch * 8];
            }
#pragma unroll
        for (int ni = 0; ni < 4; ++ni)
#pragma unroll
            for (int hh = 0; hh < 2; ++hh) {
                int row = ni * 16 + l15;
                int ch  = (hh * 4 + quad) ^ (row & 7);
                bfr[ni][hh] = *(const bf16x8*)&Bs[pb][row * 64 + ch * 8];
            }
#pragma unroll
        for (int mi = 0; mi < 4; ++mi)
#pragma unroll
            for (int ni = 0; ni < 4; ++ni) {
                acc[mi][ni] = __builtin_amdgcn_mfma_f32_16x16x32_bf16(af[mi][0], bfr[ni][0], acc[mi][ni], 0, 0, 0);
                acc[mi][ni] = __builtin_amdgcn_mfma_f32_16x16x32_bf16(af[mi][1], bfr[ni][1], acc[mi][ni], 0, 0, 0);
            }
    };

    // ---- prologue
    if (producer) {
        prefetch(0, wgs0, crs0);
        build(0, 0, wgs0, crs0);
        prefetch(1, wgs1, crs1);
    }
    __syncthreads();

    // ---- 36 steps, manually 2-unrolled for static buffer/set parity
    for (int sp = 0; sp < 18; ++sp) {
        const int s = sp * 2;
        if (producer) {
            if (s < 35) build(1, s + 1, wgs1, crs1);
            if (s + 2 < 36) prefetch(s + 2, wgs0, crs0);
        } else {
            mfma_step(0);
        }
        __syncthreads();
        if (producer) {
            if (s + 2 < 36) build(0, s + 2, wgs0, crs0);
            if (s + 3 < 36) prefetch(s + 3, wgs1, crs1);
        } else {
            mfma_step(1);
        }
        __syncthreads();
    }

    // ---- epilogue (consumers only): D layout col = lane&15, row = quad*4+reg
    if (!producer) {
        float* opnt = out + (size_t)n * COUT * HW + hw0;
#pragma unroll
        for (int mi = 0; mi < 4; ++mi)
#pragma unroll
            for (int ni = 0; ni < 4; ++ni) {
                int col = ni * 16 + l15;
#pragma unroll
                for (int rr = 0; rr < 4; ++rr) {
                    int row = wv * 64 + mi * 16 + quad * 4 + rr;
                    opnt[(size_t)row * HW + col] = acc[mi][ni][rr];
                }
            }
    }
}

// --------------------------------------------------------------- launch ----
extern "C" void kernel_launch(void* const* d_in, const int* in_sizes, int n_in,
                              void* d_out, int out_size, void* d_ws, size_t ws_size,
                              hipStream_t stream) {
    const float* x   = (const float*)d_in[0];   // [16][256][32][32]
    const float* off = (const float*)d_in[1];   // [16][1024][18]
    const float* wt  = (const float*)d_in[2];   // [256][256][3][3]
    float* out = (float*)d_out;                 // [16][256][32][32]

    unsigned short* wbf = (unsigned short*)d_ws;                        // 1179648 B
    unsigned short* xtb = (unsigned short*)((char*)d_ws + 1179648);     // 8388608 B

    wconv_kernel<<<256, 256, 0, stream>>>(wt, wbf);
    xt_kernel<<<dim3(4, 16, 16), 256, 0, stream>>>(x, xtb);
    fused_kernel<<<256, 512, 0, stream>>>(wbf, xtb, off, out);
}

// Round 8
// 127.089 us; speedup vs baseline: 1.0728x; 1.0728x over previous
//
#include <hip/hip_runtime.h>
#include <hip/hip_bf16.h>

// Problem constants
#define NB   16
#define CIN  256
#define COUT 256
#define HH   32
#define WW   32
#define HW   1024           // 32*32
#define KK   9
#define CK   2304           // CIN*KK  (ordered k*256 + c, tap-major)

typedef __bf16 bf16x8 __attribute__((ext_vector_type(8)));
typedef float  f32x4  __attribute__((ext_vector_type(4)));

__device__ __forceinline__ unsigned short f2bf(float f) {
    unsigned int u = __float_as_uint(f);
    u += 0x7FFFu + ((u >> 16) & 1u);          // round-nearest-even
    return (unsigned short)(u >> 16);
}
__device__ __forceinline__ float bfhi(unsigned int u) {   // high bf16 -> f32
    return __uint_as_float(u & 0xFFFF0000u);
}
__device__ __forceinline__ float bflo(unsigned int u) {   // low bf16 -> f32
    return __uint_as_float(u << 16);
}

// ---------------------------------------------------------------- wconv ----
// weight fp32 [O][C][3][3] -> bf16 [O][k*256+c]  (tap-major)
__global__ __launch_bounds__(256) void wconv_kernel(const float* __restrict__ w,
                                                    unsigned short* __restrict__ wbf) {
    __shared__ float ls[CK];
    const int o = blockIdx.x;
    const float* wo = w + (size_t)o * CK;
#pragma unroll
    for (int i = threadIdx.x; i < CK; i += 256) ls[i] = wo[i];
    __syncthreads();
    unsigned short* dst = wbf + (size_t)o * CK;
#pragma unroll
    for (int i = threadIdx.x; i < CK; i += 256) {
        int k = i >> 8, c = i & 255;
        dst[i] = f2bf(ls[c * KK + k]);        // bank stride 9: conflict-free
    }
}

// ------------------------------------------------------------------- xt ----
// x fp32 [n][c][hw] -> xtb bf16 [n][hw][c]   (64x64 LDS tile transpose)
__global__ __launch_bounds__(256) void xt_kernel(const float* __restrict__ x,
                                                 unsigned short* __restrict__ xtb) {
    __shared__ float ls[64][65];
    const int c0  = blockIdx.x * 64;
    const int hw0 = blockIdx.y * 64;
    const int n   = blockIdx.z;
    const int t   = threadIdx.x;
    {
        int c = t >> 2, q = t & 3;
        const float4* base = (const float4*)(x + ((size_t)(n * CIN + c0 + c)) * HW + hw0 + q * 16);
#pragma unroll
        for (int j = 0; j < 4; ++j) {
            float4 v = base[j];
            ls[c][q * 16 + j * 4 + 0] = v.x;
            ls[c][q * 16 + j * 4 + 1] = v.y;
            ls[c][q * 16 + j * 4 + 2] = v.z;
            ls[c][q * 16 + j * 4 + 3] = v.w;
        }
    }
    __syncthreads();
    {
        int hw = t >> 2, seg = (t & 3) * 16;
        unsigned int dw[8];
#pragma unroll
        for (int j = 0; j < 8; ++j) {
            float f0 = ls[seg + 2 * j][hw];
            float f1 = ls[seg + 2 * j + 1][hw];
            dw[j] = (unsigned)f2bf(f0) | ((unsigned)f2bf(f1) << 16);
        }
        uint4* dst = (uint4*)(xtb + ((size_t)(n * HW + hw0 + hw)) * CIN + c0 + seg);
        dst[0] = *(uint4*)&dw[0];
        dst[1] = *(uint4*)&dw[4];
    }
}

// ---------------------------------------------------------------- fused ----
// Per block: out[0..255][hw0..hw0+63] for one image. BM=256, BN=64, BK=64.
// 512 threads / 8 waves, wave tile 32(o) x 64(hw).
// NO A-tile in LDS: A-fragments load global->VGPR directly (each A row is
// consumed by exactly one wave), double-buffered one step ahead. LDS holds
// only the B tile (Bs[2], 16 KB, XOR-swizzled); corners prefetched one step
// ahead. Barriers therefore need only lgkmcnt (no lds-DMA vmcnt drain);
// global loads wait at their use point a full step after issue.
// XCD-aware block decode keeps each image's xtb slice + wbf in one XCD L2.
__global__ __launch_bounds__(512, 2) void fused_kernel(const unsigned short* __restrict__ wbf,
                                                       const unsigned short* __restrict__ xtb,
                                                       const float* __restrict__ off,
                                                       float* __restrict__ out) {
    __shared__ unsigned short Bs[2][64 * 64];    // 16 KB

    const int tid  = threadIdx.x;
    const int wv   = tid >> 6;                // 0..7  (M position, 32 rows each)
    const int lane = tid & 63;
    const int quad = lane >> 4;
    const int l15  = lane & 15;

    const int hwl = tid >> 3;                 // 0..63  (B row this thread builds)
    const int seg = tid & 7;                  // 8-channel segment within 64

    // XCD-aware decode (consecutive ids round-robin XCDs)
    const int id  = blockIdx.x;
    const int n   = ((id & 7) << 1) | ((id >> 3) & 1);
    const int hw0 = (id >> 4) * 64;

    const int hw = hw0 + hwl;
    const int h  = hw >> 5, w = hw & 31;

    const uint4*  xb4  = (const uint4*)(xtb + (size_t)n * HW * CIN);
    const float2* offp = (const float2*)(off + ((size_t)n * HW + hw) * (2 * KK));
    const unsigned short* Abase = wbf + (size_t)(wv * 32 + l15) * CK + quad * 8;

    f32x4 acc[2][4] = {};

    auto setup = [&](int tap, float wg[4], int ix[4]) {
        float2 o = offp[tap];
        float py = (float)(h + tap / 3 - 1) + o.x;
        float px = (float)(w + tap % 3 - 1) + o.y;
        float y0f = floorf(py), x0f = floorf(px);
        float ly = py - y0f, lx = px - x0f;
        int y0 = (int)y0f, x0 = (int)x0f;
#pragma unroll
        for (int c2 = 0; c2 < 4; ++c2) {
            int yy = y0 + (c2 >> 1);
            int xx = x0 + (c2 & 1);
            float wy = (c2 >> 1) ? ly : 1.0f - ly;
            float wx = (c2 & 1) ? lx : 1.0f - lx;
            bool v = (yy >= 0) && (yy < HH) && (xx >= 0) && (xx < WW);
            wg[c2] = v ? wy * wx : 0.0f;
            int yc = yy < 0 ? 0 : (yy > HH - 1 ? HH - 1 : yy);
            int xc = xx < 0 ? 0 : (xx > WW - 1 ? WW - 1 : xx);
            ix[c2] = yc * WW + xc;
        }
    };

    // corners for step s (sub = s&3) into cr
    auto loadc = [&](uint4 cr[4], const int ix[4], int s) {
        int sub = s & 3;
#pragma unroll
        for (int c2 = 0; c2 < 4; ++c2)
            cr[c2] = xb4[(size_t)ix[c2] * 32 + sub * 8 + seg];
    };

    // A-fragments for step s, direct global->VGPR
    auto loada = [&](bf16x8 af[2][2], int s) {
        const unsigned short* p = Abase + s * 64;
#pragma unroll
        for (int mi = 0; mi < 2; ++mi)
#pragma unroll
            for (int hh = 0; hh < 2; ++hh)
                af[mi][hh] = *(const bf16x8*)(p + (size_t)mi * 16 * CK + hh * 32);
    };

    // lerp corners -> bf16 pairs -> swizzled ds_write_b128 into Bs[nb]
    auto buildB = [&](int nb, const uint4 cr[4], const float wg[4]) {
        unsigned u0[4], u1[4], u2[4], u3[4];
        *(uint4*)u0 = cr[0]; *(uint4*)u1 = cr[1];
        *(uint4*)u2 = cr[2]; *(uint4*)u3 = cr[3];
        unsigned dw[4];
#pragma unroll
        for (int d = 0; d < 4; ++d) {
            float2 lv;
            lv.x = wg[0] * bflo(u0[d]) + wg[1] * bflo(u1[d])
                 + wg[2] * bflo(u2[d]) + wg[3] * bflo(u3[d]);
            lv.y = wg[0] * bfhi(u0[d]) + wg[1] * bfhi(u1[d])
                 + wg[2] * bfhi(u2[d]) + wg[3] * bfhi(u3[d]);
            __hip_bfloat162 bb = __float22bfloat162_rn(lv);
            dw[d] = *(unsigned*)&bb;
        }
        *(uint4*)&Bs[nb][hwl * 64 + (seg ^ (hwl & 7)) * 8] = *(uint4*)dw;
    };

    auto mfma_step = [&](int pb, const bf16x8 af[2][2]) {
        bf16x8 bfr[4][2];
#pragma unroll
        for (int ni = 0; ni < 4; ++ni)
#pragma unroll
            for (int hh = 0; hh < 2; ++hh) {
                int row = ni * 16 + l15;
                int ch  = (hh * 4 + quad) ^ (row & 7);
                bfr[ni][hh] = *(const bf16x8*)&Bs[pb][row * 64 + ch * 8];
            }
#pragma unroll
        for (int mi = 0; mi < 2; ++mi)
#pragma unroll
            for (int ni = 0; ni < 4; ++ni) {
                acc[mi][ni] = __builtin_amdgcn_mfma_f32_16x16x32_bf16(af[mi][0], bfr[ni][0], acc[mi][ni], 0, 0, 0);
                acc[mi][ni] = __builtin_amdgcn_mfma_f32_16x16x32_bf16(af[mi][1], bfr[ni][1], acc[mi][ni], 0, 0, 0);
            }
    };

    // ---- prologue: corners(0),(1); A(0); build B(0)
    float wgc[4], wgn[4];
    int   ixc[4], ixn[4];
    uint4 crE[4], crO[4];
    bf16x8 afE[2][2], afO[2][2];

    setup(0, wgc, ixc);
    loadc(crE, ixc, 0);
    loadc(crO, ixc, 1);
    loada(afE, 0);
    buildB(0, crE, wgc);
    __syncthreads();

    // ---- 36 steps (9 taps x 4 sub-steps), one barrier per step.
    // Step order: build B(next) | prefetch corners(step+2) | load A(next)
    //             | MFMA(cur) | barrier.
    for (int tap = 0; tap < 9; ++tap) {
        const int b = tap * 4;
        // step b+0: compute (Bs0, afE)
        buildB(1, crO, wgc);                  // B(b+1)
        loadc(crE, ixc, b + 2);
        loada(afO, b + 1);
        mfma_step(0, afE);
        __syncthreads();
        // step b+1: compute (Bs1, afO)
        buildB(0, crE, wgc);                  // B(b+2)
        loadc(crO, ixc, b + 3);
        loada(afE, b + 2);
        mfma_step(1, afO);
        __syncthreads();
        // step b+2: compute (Bs0, afE)
        buildB(1, crO, wgc);                  // B(b+3)
        if (tap < 8) { setup(tap + 1, wgn, ixn); loadc(crE, ixn, b + 4); }
        loada(afO, b + 3);
        mfma_step(0, afE);
        __syncthreads();
        // step b+3: compute (Bs1, afO)
        if (tap < 8) {
            buildB(0, crE, wgn);              // B(b+4)
            loadc(crO, ixn, b + 5);
            loada(afE, b + 4);
#pragma unroll
            for (int c2 = 0; c2 < 4; ++c2) { wgc[c2] = wgn[c2]; ixc[c2] = ixn[c2]; }
            mfma_step(1, afO);
            __syncthreads();
        } else {
            mfma_step(1, afO);
        }
    }

    // ---- epilogue: D layout col = lane&15, row = quad*4 + reg
    float* opnt = out + (size_t)n * COUT * HW + hw0;
#pragma unroll
    for (int mi = 0; mi < 2; ++mi)
#pragma unroll
        for (int ni = 0; ni < 4; ++ni) {
            int col = ni * 16 + l15;
#pragma unroll
            for (int rr = 0; rr < 4; ++rr) {
                int row = wv * 32 + mi * 16 + quad * 4 + rr;
                opnt[(size_t)row * HW + col] = acc[mi][ni][rr];
            }
        }
}

// --------------------------------------------------------------- launch ----
extern "C" void kernel_launch(void* const* d_in, const int* in_sizes, int n_in,
                              void* d_out, int out_size, void* d_ws, size_t ws_size,
                              hipStream_t stream) {
    const float* x   = (const float*)d_in[0];   // [16][256][32][32]
    const float* off = (const float*)d_in[1];   // [16][1024][18]
    const float* wt  = (const float*)d_in[2];   // [256][256][3][3]
    float* out = (float*)d_out;                 // [16][256][32][32]

    unsigned short* wbf = (unsigned short*)d_ws;                        // 1179648 B
    unsigned short* xtb = (unsigned short*)((char*)d_ws + 1179648);     // 8388608 B

    wconv_kernel<<<256, 256, 0, stream>>>(wt, wbf);
    xt_kernel<<<dim3(4, 16, 16), 256, 0, stream>>>(x, xtb);
    fused_kernel<<<256, 512, 0, stream>>>(wbf, xtb, off, out);
}